// Round 2
// baseline (620.932 us; speedup 1.0000x reference)
//
#include <hip/hip_runtime.h>
#include <math.h>

#define L 1024
#define B 256
#define D 256
#define T 50
#define H 8
#define BD 65536  // B*D

#define NEG_BIG (-1e30f)

// ---------------------------------------------------------------------------
// DPP helpers: intra-16-lane all-reduce sum, zero DS-pipe ops.
// Classic CDNA codes: quad_perm xor1=0xB1, xor2=0x4E, row_half_mirror=0x141,
// row_mirror=0x140.
// ---------------------------------------------------------------------------
template <int CTRL>
__device__ __forceinline__ float dpp_movf(float x) {
  return __int_as_float(
      __builtin_amdgcn_update_dpp(0, __float_as_int(x), CTRL, 0xF, 0xF, false));
}

__device__ __forceinline__ float row16_sum(float x) {
  x += dpp_movf<0xB1>(x);   // pair sum   (xor 1)
  x += dpp_movf<0x4E>(x);   // quad sum   (xor 2)
  x += dpp_movf<0x141>(x);  // 8-lane sum (half mirror)
  x += dpp_movf<0x140>(x);  // 16-lane sum (mirror)
  return x;
}

// ---------------------------------------------------------------------------
// K1: hbar_sum[b*256+d] = sum_l ebp[l,b,d]   (mean division folded into K2)
// grid (64, 16) x 256 threads.
// ---------------------------------------------------------------------------
__global__ __launch_bounds__(256) void k_mean(const float* __restrict__ ebp,
                                              float* __restrict__ hbar) {
  const int slot = blockIdx.x * 1024 + threadIdx.x * 4;
  const float* p = ebp + (size_t)blockIdx.y * 64 * BD + slot;
  float ax = 0.f, ay = 0.f, az = 0.f, aw = 0.f;
  float bx = 0.f, by = 0.f, bz = 0.f, bw = 0.f;
  for (int i = 0; i < 64; i += 4) {
    float4 x0 = *(const float4*)(p + (size_t)(i + 0) * BD);
    float4 x1 = *(const float4*)(p + (size_t)(i + 1) * BD);
    float4 x2 = *(const float4*)(p + (size_t)(i + 2) * BD);
    float4 x3 = *(const float4*)(p + (size_t)(i + 3) * BD);
    ax += x0.x + x1.x; ay += x0.y + x1.y; az += x0.z + x1.z; aw += x0.w + x1.w;
    bx += x2.x + x3.x; by += x2.y + x3.y; bz += x2.z + x3.z; bw += x2.w + x3.w;
  }
  atomicAdd(&hbar[slot + 0], ax + bx);
  atomicAdd(&hbar[slot + 1], ay + by);
  atomicAdd(&hbar[slot + 2], az + bz);
  atomicAdd(&hbar[slot + 3], aw + bw);
}

// ---------------------------------------------------------------------------
// K2: per b: context = [hbar/1024 | ebp[a_last,b] | ebp[a_first,b]] (768)
//     q1 = context @ Wq1; qk1[h][e] = (1/sqrt(32)) * sum_d Wk1[e,h*32+d]*q1[h*32+d]
// grid 256 x 256 threads.
// ---------------------------------------------------------------------------
__global__ __launch_bounds__(256) void k_context(
    const float* __restrict__ ebp, const int* __restrict__ pa,
    const float* __restrict__ Wq1, const float* __restrict__ Wk1,
    const float* __restrict__ hbar, float* __restrict__ qk1out) {
  __shared__ float ctx[768];
  __shared__ float q1[256];
  const int b = blockIdx.x, t = threadIdx.x;
  const int aLast = pa[b * T + (T - 1)];
  const int aFirst = pa[b * T + 0];
  ctx[t] = hbar[b * 256 + t] * (1.0f / 1024.0f);
  ctx[256 + t] = ebp[(size_t)aLast * BD + b * 256 + t];
  ctx[512 + t] = ebp[(size_t)aFirst * BD + b * 256 + t];
  __syncthreads();
  float acc = 0.f;
  for (int i = 0; i < 768; i++) acc += ctx[i] * Wq1[i * 256 + t];
  q1[t] = acc;
  __syncthreads();
  const float sc = 0.17677669529663687f;  // 1/sqrt(32)
  #pragma unroll
  for (int h = 0; h < H; h++) {
    float a = 0.f;
    #pragma unroll
    for (int d = 0; d < 32; d++) a += Wk1[t * 256 + h * 32 + d] * q1[h * 32 + d];
    qk1out[b * 2048 + h * 256 + t] = a * sc;
  }
}

// ---------------------------------------------------------------------------
// K3: per b: flash pass over l -> ve[h][e] -> head_out -> context2 -> q2 -> qk2
// grid 256 x 512 threads (8 waves; wave w handles l = w, w+8, ...).
// Lane owns e = lane*4..lane*4+3. Score reduce: DPP row16 + select + 2 shfl
// + 7-shfl gather. Accumulator slot ii on a lane holds head ((lane&7)^ii).
// ---------------------------------------------------------------------------
__global__ __launch_bounds__(512) void k_attn(
    const float* __restrict__ ebp, const int* __restrict__ pa,
    const float* __restrict__ qk1, const float* __restrict__ Wv1,
    const float* __restrict__ Wo1, const float* __restrict__ Wq2,
    const float* __restrict__ Wk2, float* __restrict__ qk2out) {
  __shared__ float ve_s[8][2048];
  __shared__ float ms_s[8][8];
  __shared__ float ss_s[8][8];
  __shared__ unsigned bmp[32];
  __shared__ float ho_s[256];
  __shared__ float c2_s[256];
  __shared__ float q2_s[256];

  const int b = blockIdx.x, t = threadIdx.x;
  const int w = t >> 6, lane = t & 63, j = lane & 7;

  if (t < 32) bmp[t] = 0u;
  __syncthreads();
  if (t < T) {
    int a = pa[b * T + t];
    atomicOr(&bmp[a >> 5], 1u << (a & 31));
  }
  __syncthreads();

  // qk1 fragments straight from global (L2-resident, 8 KiB per b)
  float qkr[8][4];
  #pragma unroll
  for (int h = 0; h < H; h++) {
    float4 v = *(const float4*)&qk1[b * 2048 + h * 256 + lane * 4];
    qkr[h][0] = v.x; qkr[h][1] = v.y; qkr[h][2] = v.z; qkr[h][3] = v.w;
  }
  float m[8], s[8], ve[8][4];
  #pragma unroll
  for (int ii = 0; ii < 8; ii++) {
    m[ii] = NEG_BIG; s[ii] = 0.f;
    ve[ii][0] = ve[ii][1] = ve[ii][2] = ve[ii][3] = 0.f;
  }

  const float* src = ebp + b * 256 + lane * 4;
  float4 x0 = *(const float4*)(src + (size_t)w * BD);
  float4 x1 = *(const float4*)(src + (size_t)(w + 8) * BD);
  for (int i = 0; i < 128; i++) {
    const int l = w + 8 * i;
    const int lp = l + 16;
    float4 xn = *(const float4*)(src + (size_t)(lp < L ? lp : l) * BD);
    if (!((bmp[l >> 5] >> (l & 31)) & 1u)) {
      float p[8];
      #pragma unroll
      for (int h = 0; h < H; h++)
        p[h] = x0.x * qkr[h][0] + x0.y * qkr[h][1] + x0.z * qkr[h][2] + x0.w * qkr[h][3];
      #pragma unroll
      for (int h = 0; h < H; h++) p[h] = row16_sum(p[h]);
      // v = p[j]  (select tree, 7 cndmask)
      float a0 = (j & 1) ? p[1] : p[0];
      float a1 = (j & 1) ? p[3] : p[2];
      float a2 = (j & 1) ? p[5] : p[4];
      float a3 = (j & 1) ? p[7] : p[6];
      float b0 = (j & 2) ? a1 : a0;
      float b1 = (j & 2) ? a3 : a2;
      float v = (j & 4) ? b1 : b0;
      // cross-row: full score of head j on every lane
      v += __shfl_xor(v, 16);
      v += __shfl_xor(v, 32);
      // gather all 8 heads: arr[ii] = score of head (j ^ ii)
      float arr[8];
      arr[0] = v;
      arr[1] = __shfl_xor(arr[0], 1);
      arr[2] = __shfl_xor(arr[0], 2);
      arr[3] = __shfl_xor(arr[1], 2);
      arr[4] = __shfl_xor(arr[0], 4);
      arr[5] = __shfl_xor(arr[1], 4);
      arr[6] = __shfl_xor(arr[2], 4);
      arr[7] = __shfl_xor(arr[3], 4);
      // online softmax update, slot ii = head j^ii
      #pragma unroll
      for (int ii = 0; ii < 8; ii++) {
        float sc = arr[ii];
        float nm = fmaxf(m[ii], sc);
        float dd = __expf(sc - nm);
        if (nm > m[ii]) {
          float al = __expf(m[ii] - nm);
          s[ii] *= al;
          ve[ii][0] *= al; ve[ii][1] *= al; ve[ii][2] *= al; ve[ii][3] *= al;
          m[ii] = nm;
        }
        s[ii] += dd;
        ve[ii][0] += dd * x0.x; ve[ii][1] += dd * x0.y;
        ve[ii][2] += dd * x0.z; ve[ii][3] += dd * x0.w;
      }
    }
    x0 = x1; x1 = xn;
  }

  // dump per-wave state (head mapping j^ii only changes the address)
  #pragma unroll
  for (int ii = 0; ii < 8; ii++) {
    const int h = j ^ ii;
    *(float4*)&ve_s[w][h * 256 + lane * 4] =
        make_float4(ve[ii][0], ve[ii][1], ve[ii][2], ve[ii][3]);
  }
  if (lane == 0) {  // j==0 -> slot ii is head ii
    #pragma unroll
    for (int ii = 0; ii < 8; ii++) { ms_s[w][ii] = m[ii]; ss_s[w][ii] = s[ii]; }
  }
  __syncthreads();

  // merge 8 wave-states; ve_s[0][sidx] <- normalized ve (per-slot ownership)
  for (int sidx = t; sidx < 2048; sidx += 512) {
    const int h = sidx >> 8;
    float M = ms_s[0][h];
    #pragma unroll
    for (int w2 = 1; w2 < 8; w2++) M = fmaxf(M, ms_s[w2][h]);
    float S = 0.f, V = 0.f;
    #pragma unroll
    for (int w2 = 0; w2 < 8; w2++) {
      float al = __expf(ms_s[w2][h] - M);
      S += ss_s[w2][h] * al;
      V += ve_s[w2][sidx] * al;
    }
    ve_s[0][sidx] = V / S;
  }
  __syncthreads();

  // head_out[h][d] = sum_e ve[h][e] * Wv1[e, h*32+d]
  if (t < 256) {
    const int h = t >> 5, dd = t & 31;
    float acc = 0.f;
    for (int e = 0; e < 256; e++) acc += ve_s[0][h * 256 + e] * Wv1[e * 256 + h * 32 + dd];
    ho_s[t] = acc;
  }
  __syncthreads();
  if (t < 256) {  // context2
    float acc = 0.f;
    for (int i = 0; i < 256; i++) acc += ho_s[i] * Wo1[i * 256 + t];
    c2_s[t] = acc;
  }
  __syncthreads();
  if (t < 256) {  // q2
    float acc = 0.f;
    for (int i = 0; i < 256; i++) acc += c2_s[i] * Wq2[i * 256 + t];
    q2_s[t] = acc;
  }
  __syncthreads();
  if (t < 256) {  // qk2 = (1/16) Wk2 @ q2
    float acc = 0.f;
    for (int jq = 0; jq < 256; jq++) acc += Wk2[t * 256 + jq] * q2_s[jq];
    qk2out[b * 256 + t] = acc * 0.0625f;
  }
}

// ---------------------------------------------------------------------------
// K4: fs[l] = ebp[l,b,:].qk2[b,:]; lp = 10*tanh(fs) (+mask); softmax over l.
// grid 256 x 512 threads.
// ---------------------------------------------------------------------------
__global__ __launch_bounds__(512) void k_final(
    const float* __restrict__ ebp, const int* __restrict__ pa,
    const float* __restrict__ qk2, float* __restrict__ out) {
  __shared__ float fs_s[1024];
  __shared__ unsigned bmp[32];
  __shared__ float red[16];
  const int b = blockIdx.x, t = threadIdx.x;
  const int w = t >> 6, lane = t & 63;
  if (t < 32) bmp[t] = 0u;
  __syncthreads();
  if (t < T) {
    int a = pa[b * T + t];
    atomicOr(&bmp[a >> 5], 1u << (a & 31));
  }
  __syncthreads();

  float4 q = *(const float4*)&qk2[b * 256 + lane * 4];
  const float* src = ebp + b * 256 + lane * 4;
  float4 x0 = *(const float4*)(src + (size_t)w * BD);
  float4 x1 = *(const float4*)(src + (size_t)(w + 8) * BD);
  for (int i = 0; i < 128; i++) {
    const int l = w + 8 * i;
    const int lp = l + 16;
    float4 xn = *(const float4*)(src + (size_t)(lp < L ? lp : l) * BD);
    if ((bmp[l >> 5] >> (l & 31)) & 1u) {
      if (lane == 0) fs_s[l] = NEG_BIG;
    } else {
      float p = x0.x * q.x + x0.y * q.y + x0.z * q.z + x0.w * q.w;
      p = row16_sum(p);
      p += __shfl_xor(p, 16);
      p += __shfl_xor(p, 32);
      if (lane == 0) fs_s[l] = 10.f * tanhf(p);
    }
    x0 = x1; x1 = xn;
  }
  __syncthreads();

  const float v0 = fs_s[t], v1 = fs_s[t + 512];
  float ml = fmaxf(v0, v1);
  #pragma unroll
  for (int d = 1; d < 64; d <<= 1) ml = fmaxf(ml, __shfl_xor(ml, d, 64));
  if (lane == 0) red[w] = ml;
  __syncthreads();
  float M = red[0];
  #pragma unroll
  for (int i = 1; i < 8; i++) M = fmaxf(M, red[i]);
  const float e0 = __expf(v0 - M), e1 = __expf(v1 - M);
  float sl = e0 + e1;
  #pragma unroll
  for (int d = 1; d < 64; d <<= 1) sl += __shfl_xor(sl, d, 64);
  if (lane == 0) red[8 + w] = sl;
  __syncthreads();
  float S = 0.f;
  #pragma unroll
  for (int i = 0; i < 8; i++) S += red[8 + i];
  const float inv = 1.f / S;
  out[(size_t)t * B + b] = e0 * inv;
  out[(size_t)(t + 512) * B + b] = e1 * inv;
}

// ---------------------------------------------------------------------------
extern "C" void kernel_launch(void* const* d_in, const int* in_sizes, int n_in,
                              void* d_out, int out_size, void* d_ws, size_t ws_size,
                              hipStream_t stream) {
  const float* ebp = (const float*)d_in[0];
  const int* pa = (const int*)d_in[1];
  const float* Wq1 = (const float*)d_in[2];
  const float* Wk1 = (const float*)d_in[3];
  const float* Wv1 = (const float*)d_in[4];
  const float* Wo1 = (const float*)d_in[5];
  const float* Wq2 = (const float*)d_in[6];
  const float* Wk2 = (const float*)d_in[7];
  float* out = (float*)d_out;
  float* ws = (float*)d_ws;

  float* hbar = ws;                  // 65536 floats (sum over l; /1024 in K2)
  float* qk1 = ws + 65536;           // B*H*256 = 524288 floats
  float* qk2 = ws + 65536 + 524288;  // B*256  = 65536 floats

  hipMemsetAsync(hbar, 0, 65536 * sizeof(float), stream);
  k_mean<<<dim3(64, 16), 256, 0, stream>>>(ebp, hbar);
  k_context<<<256, 256, 0, stream>>>(ebp, pa, Wq1, Wk1, hbar, qk1);
  k_attn<<<256, 512, 0, stream>>>(ebp, pa, qk1, Wv1, Wo1, Wq2, Wk2, qk2);
  k_final<<<256, 512, 0, stream>>>(ebp, pa, qk2, out);
}